// Round 14
// baseline (8953.094 us; speedup 1.0000x reference)
//
#include <hip/hip_runtime.h>

#define BB 32
#define TT 150
#define LL 400
#define FEATD 512
#define RNND 512
#define ATTD 512
#define EMBD 256
#define VOCABD 5000
#define G3 1536

__device__ __forceinline__ float fsigmoid(float x) { return 1.f / (1.f + __expf(-x)); }
__device__ __forceinline__ float ftanh(float x) {
    x = fminf(15.f, fmaxf(-15.f, x));
    float e = __expf(2.f * x);
    return 1.f - 2.f / (e + 1.f);
}
__device__ __forceinline__ void fma4(float4& a, const float4 w, const float s) {
    a.x += w.x * s; a.y += w.y * s; a.z += w.z * s; a.w += w.w * s;
}

// ---------------- one-time GEMMs: fp = feats@W1, G = feats@outW_bot (merged) ----------------
__global__ void __launch_bounds__(256) k_proj2(const float* __restrict__ features,
                                               const float* __restrict__ W1,
                                               const float* __restrict__ WG,
                                               float* __restrict__ fp,
                                               float* __restrict__ G) {
    __shared__ float sa[64 * 68];
    int half = blockIdx.x >= 800;
    const float* W = half ? WG : W1;
    float* outb = half ? G : fp;
    int bid = half ? blockIdx.x - 800 : blockIdx.x;
    int blt = bid >> 2, at = bid & 3;
    int bl0 = blt * 64;
    int tid = threadIdx.x;
    int aq = tid & 31, blg = tid >> 5;
    float4 acc[8] = {};
    for (int kc = 0; kc < FEATD; kc += 64) {
        __syncthreads();
        for (int it = 0; it < 16; ++it) {
            int lin = it * 256 + tid;
            int k = lin & 63, bl = lin >> 6;
            sa[k * 68 + bl] = features[((size_t)bl0 + bl) * FEATD + kc + k];
        }
        __syncthreads();
#pragma unroll 4
        for (int k = 0; k < 64; ++k) {
            float4 w = *(const float4*)&W[(size_t)(kc + k) * 512 + at * 128 + aq * 4];
            float4 s0 = *(const float4*)&sa[k * 68 + blg * 8];
            float4 s1 = *(const float4*)&sa[k * 68 + blg * 8 + 4];
            fma4(acc[0], w, s0.x); fma4(acc[1], w, s0.y);
            fma4(acc[2], w, s0.z); fma4(acc[3], w, s0.w);
            fma4(acc[4], w, s1.x); fma4(acc[5], w, s1.y);
            fma4(acc[6], w, s1.z); fma4(acc[7], w, s1.w);
        }
    }
#pragma unroll
    for (int i = 0; i < 8; ++i)
        *(float4*)&outb[((size_t)bl0 + blg * 8 + i) * 512 + at * 128 + aq * 4] = acc[i];
}

// ---------------- K1: gate GEMM partials + inline lo(t-1). 120 blocks x 512 ----------------
// mx: [emb(tok) | lo(t-1)] (K=768) @ Wk -> mxp[3], mh: h(t-1) @ Wr -> mhp[2].
// lo(t-1) = tanh(hpart + gdot/esum); hpart final [b][512], gdotT [b][512][8].
// jt==0 lo-blocks write los[t] for the final logits GEMM.
__global__ void __launch_bounds__(512) k_gates(
    const float* __restrict__ emb, const int* __restrict__ formula,
    const float* __restrict__ Wk, const float* __restrict__ Wr,
    const float* __restrict__ hin, const float* __restrict__ hpart,
    const float* __restrict__ gdotT, const float* __restrict__ esumT,
    float* __restrict__ mxp, float* __restrict__ mhp,
    float* __restrict__ los, int t) {
    __shared__ float sm[256 * 33];
    __shared__ float sinv[BB];
    __shared__ int stok[BB];
    int id = blockIdx.x, tid = threadIdx.x;
    bool isMX = id < 72;
    int jt, ks; const float* W; float* ob;
    if (isMX) { jt = id / 3; ks = id % 3; W = Wk; ob = mxp; }
    else { int r = id - 72; jt = r >> 1; ks = r & 1; W = Wr; ob = mhp; }
    int k0 = ks * 256;
    if (isMX && ks == 0 && tid < BB) stok[tid] = formula[tid * TT + t];
    if (isMX && ks > 0 && t > 0 && tid < BB) {
        float4 e0 = *(const float4*)&esumT[tid * 8];
        float4 e1 = *(const float4*)&esumT[tid * 8 + 4];
        sinv[tid] = 1.f / (e0.x + e0.y + e0.z + e0.w + e1.x + e1.y + e1.z + e1.w);
    }
    __syncthreads();
    for (int it = 0; it < 16; ++it) {
        int lin = it * 512 + tid;
        int k = lin & 255, b = lin >> 8;
        float v;
        if (!isMX) {
            v = hin[(size_t)b * RNND + k0 + k];
        } else if (ks == 0) {
            v = emb[(size_t)stok[b] * EMBD + k];
        } else {
            int kr = (ks - 1) * 256 + k;
            if (t == 0) {
                v = 0.f;  // lo(-1) = 0
            } else {
                float hps = hpart[(size_t)b * RNND + kr];
                float4 g0 = *(const float4*)&gdotT[((size_t)b * RNND + kr) * 8];
                float4 g1 = *(const float4*)&gdotT[((size_t)b * RNND + kr) * 8 + 4];
                float gg = g0.x + g0.y + g0.z + g0.w + g1.x + g1.y + g1.z + g1.w;
                v = ftanh(hps + sinv[b] * gg);
            }
            if (jt == 0) los[((size_t)t * BB + b) * RNND + kr] = v;  // slot t = lo(t-1)
        }
        sm[k * 33 + b] = v;
    }
    __syncthreads();
    int jq = tid & 15, b = tid >> 4;
    int j = jt * 64 + jq * 4;
    float4 acc = {0, 0, 0, 0};
#pragma unroll 4
    for (int k = 0; k < 256; ++k) {
        float4 w = *(const float4*)&W[(size_t)(k0 + k) * G3 + j];
        fma4(acc, w, sm[k * 33 + b]);
    }
    *(float4*)&ob[((size_t)ks * BB + b) * G3 + j] = acc;
}

// ---------------- K2': combine -> h(t); FINAL q-slice and hpart-slice. 256 blocks x 512 ----------------
// block (ls-major, b): thread j recomputes h[j] for its b directly (26KB reads,
// no partial-staging). Then 64-col slice of q (h@W2) and hpart (h@outW_top) with
// 8-way in-block split-k -> final values, no downstream partial reduction.
// ls-major block order spreads same-weight-slice blocks across XCDs (L2 reuse).
__global__ void __launch_bounds__(512) k_qh(
    const float* __restrict__ mxp, const float* __restrict__ mhp,
    const float* __restrict__ gruB, const float* __restrict__ W2,
    const float* __restrict__ outW, const float* __restrict__ hin,
    float* __restrict__ hout, float* __restrict__ q,
    float* __restrict__ hpart) {
    __shared__ float sh[RNND];
    __shared__ float sred[512];
    int ls = blockIdx.x >> 5, b = blockIdx.x & 31;
    int tid = threadIdx.x;
    // phase 1: GRU combine -> h (thread j)
    {
        int j = tid;
        size_t m0 = ((size_t)0 * BB + b) * G3, m1 = ((size_t)1 * BB + b) * G3,
               m2 = ((size_t)2 * BB + b) * G3;
        float xz = gruB[j] + mxp[m0 + j] + mxp[m1 + j] + mxp[m2 + j];
        float xr = gruB[512 + j] + mxp[m0 + 512 + j] + mxp[m1 + 512 + j] + mxp[m2 + 512 + j];
        float xh = gruB[1024 + j] + mxp[m0 + 1024 + j] + mxp[m1 + 1024 + j] + mxp[m2 + 1024 + j];
        float rz = gruB[G3 + j] + mhp[m0 + j] + mhp[m1 + j];
        float rr = gruB[G3 + 512 + j] + mhp[m0 + 512 + j] + mhp[m1 + 512 + j];
        float rh = gruB[G3 + 1024 + j] + mhp[m0 + 1024 + j] + mhp[m1 + 1024 + j];
        float z = fsigmoid(xz + rz), r = fsigmoid(xr + rr);
        float hh = ftanh(xh + r * rh);
        float hn = z * hin[(size_t)b * RNND + j] + (1.f - z) * hh;
        sh[j] = hn;
        if (ls == 0) hout[(size_t)b * RNND + j] = hn;
    }
    __syncthreads();
    // phase 2: q-slice and hpart-slice, 8-way split-k in registers
    int c = ls * 64 + (tid & 63), kq = tid >> 6;
    int kb = kq * 64;
    float aq = 0.f, ah = 0.f;
#pragma unroll 8
    for (int k = 0; k < 64; ++k) {
        float s = sh[kb + k];
        aq += s * W2[(size_t)(kb + k) * 512 + c];
        ah += s * outW[(size_t)(kb + k) * 512 + c];
    }
    sred[tid] = aq;
    __syncthreads();
    if (tid < 64) {
        float a = 0.f;
#pragma unroll
        for (int p = 0; p < 8; ++p) a += sred[p * 64 + tid];
        q[(size_t)b * RNND + ls * 64 + tid] = a;
    }
    __syncthreads();
    sred[tid] = ah;
    __syncthreads();
    if (tid < 64) {
        float a = 0.f;
#pragma unroll
        for (int p = 0; p < 8; ++p) a += sred[p * 64 + tid];
        hpart[(size_t)b * RNND + ls * 64 + tid] = a;
    }
}

// ---------------- K3: scores + exp + gdot partials. 256 blocks x 512 ----------------
__global__ void __launch_bounds__(512) k_attn(
    const float* __restrict__ q, const float* __restrict__ V,
    const float* __restrict__ fp, const float* __restrict__ G,
    float* __restrict__ gdotT, float* __restrict__ esumT) {
    __shared__ float sq[ATTD];
    __shared__ float sV[ATTD];
    __shared__ float se[64];
    int b = blockIdx.x >> 3, ls = blockIdx.x & 7, l0 = ls * 50;
    int tid = threadIdx.x;
    sq[tid] = q[(size_t)b * RNND + tid];
    sV[tid] = V[tid];
    if (tid >= 50 && tid < 64) se[tid] = 0.f;
    __syncthreads();
    int lane = tid & 63, wv = tid >> 6;
    float4 q0 = ((const float4*)sq)[lane], q1 = ((const float4*)sq)[64 + lane];
    float4 v0 = ((const float4*)sV)[lane], v1 = ((const float4*)sV)[64 + lane];
    for (int ll = wv; ll < 50; ll += 8) {
        const float4* row = (const float4*)(fp + ((size_t)b * LL + l0 + ll) * ATTD);
        float4 f0 = row[lane], f1 = row[64 + lane];
        float d = ftanh(f0.x + q0.x) * v0.x + ftanh(f0.y + q0.y) * v0.y +
                  ftanh(f0.z + q0.z) * v0.z + ftanh(f0.w + q0.w) * v0.w +
                  ftanh(f1.x + q1.x) * v1.x + ftanh(f1.y + q1.y) * v1.y +
                  ftanh(f1.z + q1.z) * v1.z + ftanh(f1.w + q1.w) * v1.w;
#pragma unroll
        for (int o = 32; o > 0; o >>= 1) d += __shfl_xor(d, o);
        if (lane == 0) se[ll] = __expf(d);  // |score| <= sum|V| ~ 20, fp32-safe
    }
    __syncthreads();
    if (tid < 64) {
        float x = se[tid];
#pragma unroll
        for (int o = 32; o > 0; o >>= 1) x += __shfl_xor(x, o);
        if (tid == 0) esumT[b * 8 + ls] = x;
    }
    // gdot partial over this l-chunk (thread = one column)
    float a = 0.f;
#pragma unroll 2
    for (int l = 0; l < 50; ++l)
        a += se[l] * G[((size_t)b * LL + l0 + l) * RNND + tid];
    gdotT[((size_t)b * RNND + tid) * 8 + ls] = a;
}

// ---------------- tail: lo(149) -> los slot 150. 32 blocks x 512 ----------------
__global__ void __launch_bounds__(512) k_lo_tail(
    const float* __restrict__ hpart, const float* __restrict__ gdotT,
    const float* __restrict__ esumT, float* __restrict__ los) {
    int b = blockIdx.x, tid = threadIdx.x;
    float4 e0 = *(const float4*)&esumT[b * 8];
    float4 e1 = *(const float4*)&esumT[b * 8 + 4];
    float inv = 1.f / (e0.x + e0.y + e0.z + e0.w + e1.x + e1.y + e1.z + e1.w);
    float hps = hpart[(size_t)b * RNND + tid];
    float4 g0 = *(const float4*)&gdotT[((size_t)b * RNND + tid) * 8];
    float4 g1 = *(const float4*)&gdotT[((size_t)b * RNND + tid) * 8 + 4];
    float gg = g0.x + g0.y + g0.z + g0.w + g1.x + g1.y + g1.z + g1.w;
    los[((size_t)TT * BB + b) * RNND + tid] = ftanh(hps + inv * gg);
}

// ---------------- final: logits = los[1..150] @ projW ----------------
__global__ void __launch_bounds__(256) k_final(
    const float* __restrict__ los, const float* __restrict__ Wp,
    float* __restrict__ out) {
    __shared__ float sa[64 * 68];
    __shared__ unsigned srow[64];
    int mt = blockIdx.x / 40, vt = blockIdx.x % 40;
    int r0 = mt * 64;
    int tid = threadIdx.x;
    if (tid < 64) {
        int r = r0 + tid;
        int bb = r / TT, t = r % TT;
        srow[tid] = (unsigned)(((size_t)(t + 1) * BB + bb) * RNND);
    }
    int aq = tid & 31, blg = tid >> 5;
    int v = vt * 128 + aq * 4;
    bool vok = v < VOCABD;
    float4 acc[8] = {};
    __syncthreads();
    for (int kc = 0; kc < RNND; kc += 64) {
        for (int it = 0; it < 16; ++it) {
            int lin = it * 256 + tid;
            int k = lin & 63, rl = lin >> 6;
            sa[k * 68 + rl] = los[srow[rl] + kc + k];
        }
        __syncthreads();
        if (vok) {
#pragma unroll 4
            for (int k = 0; k < 64; ++k) {
                float4 w = *(const float4*)&Wp[(size_t)(kc + k) * VOCABD + v];
                float4 s0 = *(const float4*)&sa[k * 68 + blg * 8];
                float4 s1 = *(const float4*)&sa[k * 68 + blg * 8 + 4];
                fma4(acc[0], w, s0.x); fma4(acc[1], w, s0.y);
                fma4(acc[2], w, s0.z); fma4(acc[3], w, s0.w);
                fma4(acc[4], w, s1.x); fma4(acc[5], w, s1.y);
                fma4(acc[6], w, s1.z); fma4(acc[7], w, s1.w);
            }
        }
        __syncthreads();
    }
    if (vok) {
#pragma unroll
        for (int i = 0; i < 8; ++i)
            *(float4*)&out[(size_t)(r0 + blg * 8 + i) * VOCABD + v] = acc[i];
    }
}

extern "C" void kernel_launch(void* const* d_in, const int* in_sizes, int n_in,
                              void* d_out, int out_size, void* d_ws, size_t ws_size,
                              hipStream_t stream) {
    const float* features  = (const float*)d_in[0];
    const float* initstate = (const float*)d_in[1];
    const float* emb       = (const float*)d_in[2];
    const float* gruK      = (const float*)d_in[3];
    const float* gruR      = (const float*)d_in[4];
    const float* gruB      = (const float*)d_in[5];
    const float* W1        = (const float*)d_in[6];
    const float* W2        = (const float*)d_in[7];
    const float* V         = (const float*)d_in[8];
    const float* outW      = (const float*)d_in[9];
    const float* projW     = (const float*)d_in[10];
    const int*   formula   = (const int*)d_in[11];
    float* logits = (float*)d_out;

    float* ws = (float*)d_ws;
    float* h0    = ws;                                  // 16,384
    float* h1    = h0 + (size_t)BB * RNND;              // 16,384
    float* mxp   = h1 + (size_t)BB * RNND;              // 147,456
    float* mhp   = mxp + (size_t)3 * BB * G3;           // 98,304
    float* q     = mhp + (size_t)2 * BB * G3;           // 16,384
    float* hpart = q + (size_t)BB * RNND;               // 16,384
    float* gdotT = hpart + (size_t)BB * RNND;           // 131,072
    float* esumT = gdotT + (size_t)BB * RNND * 8;       // 256
    float* los   = esumT + BB * 8;                      // 151 slots: 2,473,984
    float* fp    = los + (size_t)(TT + 1) * BB * RNND;  // 6,553,600
    float* G     = fp + (size_t)BB * LL * ATTD;         // 6,553,600

    // los slot 0 = lo(-1) = zeros; re-zeroed every call (deterministic).
    hipMemsetAsync(los, 0, (size_t)BB * RNND * sizeof(float), stream);
    hipMemcpyAsync(h0, initstate, (size_t)BB * RNND * sizeof(float),
                   hipMemcpyDeviceToDevice, stream);

    k_proj2<<<1600, 256, 0, stream>>>(features, W1, outW + (size_t)512 * RNND, fp, G);

    float* hin = h0;
    float* hout = h1;
    for (int t = 0; t < TT; ++t) {
        k_gates<<<120, 512, 0, stream>>>(emb, formula, gruK, gruR, hin,
                                         hpart, gdotT, esumT, mxp, mhp, los, t);
        k_qh<<<256, 512, 0, stream>>>(mxp, mhp, gruB, W2, outW, hin, hout, q, hpart);
        k_attn<<<256, 512, 0, stream>>>(q, V, fp, G, gdotT, esumT);
        float* tmp = hin; hin = hout; hout = tmp;
    }
    k_lo_tail<<<BB, 512, 0, stream>>>(hpart, gdotT, esumT, los);
    k_final<<<75 * 40, 256, 0, stream>>>(los, projW, logits);
}

// Round 15
// 8897.510 us; speedup vs baseline: 1.0062x; 1.0062x over previous
//
#include <hip/hip_runtime.h>

#define BB 32
#define TT 150
#define LL 400
#define FEATD 512
#define RNND 512
#define ATTD 512
#define EMBD 256
#define VOCABD 5000
#define G3 1536

__device__ __forceinline__ float fsigmoid(float x) { return 1.f / (1.f + __expf(-x)); }
__device__ __forceinline__ float ftanh(float x) {
    x = fminf(15.f, fmaxf(-15.f, x));
    float e = __expf(2.f * x);
    return 1.f - 2.f / (e + 1.f);
}
__device__ __forceinline__ void fma4(float4& a, const float4 w, const float s) {
    a.x += w.x * s; a.y += w.y * s; a.z += w.z * s; a.w += w.w * s;
}

// ---------------- one-time GEMMs: fp = feats@W1, G = feats@outW_bot (merged) ----------------
__global__ void __launch_bounds__(256) k_proj2(const float* __restrict__ features,
                                               const float* __restrict__ W1,
                                               const float* __restrict__ WG,
                                               float* __restrict__ fp,
                                               float* __restrict__ G) {
    __shared__ float sa[64 * 68];
    int half = blockIdx.x >= 800;
    const float* W = half ? WG : W1;
    float* outb = half ? G : fp;
    int bid = half ? blockIdx.x - 800 : blockIdx.x;
    int blt = bid >> 2, at = bid & 3;
    int bl0 = blt * 64;
    int tid = threadIdx.x;
    int aq = tid & 31, blg = tid >> 5;
    float4 acc[8] = {};
    for (int kc = 0; kc < FEATD; kc += 64) {
        __syncthreads();
        for (int it = 0; it < 16; ++it) {
            int lin = it * 256 + tid;
            int k = lin & 63, bl = lin >> 6;
            sa[k * 68 + bl] = features[((size_t)bl0 + bl) * FEATD + kc + k];
        }
        __syncthreads();
#pragma unroll 4
        for (int k = 0; k < 64; ++k) {
            float4 w = *(const float4*)&W[(size_t)(kc + k) * 512 + at * 128 + aq * 4];
            float4 s0 = *(const float4*)&sa[k * 68 + blg * 8];
            float4 s1 = *(const float4*)&sa[k * 68 + blg * 8 + 4];
            fma4(acc[0], w, s0.x); fma4(acc[1], w, s0.y);
            fma4(acc[2], w, s0.z); fma4(acc[3], w, s0.w);
            fma4(acc[4], w, s1.x); fma4(acc[5], w, s1.y);
            fma4(acc[6], w, s1.z); fma4(acc[7], w, s1.w);
        }
    }
#pragma unroll
    for (int i = 0; i < 8; ++i)
        *(float4*)&outb[((size_t)bl0 + blg * 8 + i) * 512 + at * 128 + aq * 4] = acc[i];
}

// ---------------- K1: gate GEMM partials + inline lo(t-1). 120 blocks x 512 ----------------
// mx: [emb(tok) | lo(t-1)] (K=768) @ Wk -> mxp[3], mh: h(t-1) @ Wr -> mhp[2].
// lo(t-1) = tanh(hpart + gdot/esum); hpart final [b][512], gdotT [b][512][8].
// jt==0 lo-blocks write los[t] for the final logits GEMM.
__global__ void __launch_bounds__(512) k_gates(
    const float* __restrict__ emb, const int* __restrict__ formula,
    const float* __restrict__ Wk, const float* __restrict__ Wr,
    const float* __restrict__ hin, const float* __restrict__ hpart,
    const float* __restrict__ gdotT, const float* __restrict__ esumT,
    float* __restrict__ mxp, float* __restrict__ mhp,
    float* __restrict__ los, int t) {
    __shared__ float sm[256 * 33];
    __shared__ float sinv[BB];
    __shared__ int stok[BB];
    int id = blockIdx.x, tid = threadIdx.x;
    bool isMX = id < 72;
    int jt, ks; const float* W; float* ob;
    if (isMX) { jt = id / 3; ks = id % 3; W = Wk; ob = mxp; }
    else { int r = id - 72; jt = r >> 1; ks = r & 1; W = Wr; ob = mhp; }
    int k0 = ks * 256;
    if (isMX && ks == 0 && tid < BB) stok[tid] = formula[tid * TT + t];
    if (isMX && ks > 0 && t > 0 && tid < BB) {
        float4 e0 = *(const float4*)&esumT[tid * 8];
        float4 e1 = *(const float4*)&esumT[tid * 8 + 4];
        sinv[tid] = 1.f / (e0.x + e0.y + e0.z + e0.w + e1.x + e1.y + e1.z + e1.w);
    }
    __syncthreads();
    for (int it = 0; it < 16; ++it) {
        int lin = it * 512 + tid;
        int k = lin & 255, b = lin >> 8;
        float v;
        if (!isMX) {
            v = hin[(size_t)b * RNND + k0 + k];
        } else if (ks == 0) {
            v = emb[(size_t)stok[b] * EMBD + k];
        } else {
            int kr = (ks - 1) * 256 + k;
            if (t == 0) {
                v = 0.f;  // lo(-1) = 0
            } else {
                float hps = hpart[(size_t)b * RNND + kr];
                float4 g0 = *(const float4*)&gdotT[((size_t)b * RNND + kr) * 8];
                float4 g1 = *(const float4*)&gdotT[((size_t)b * RNND + kr) * 8 + 4];
                float gg = g0.x + g0.y + g0.z + g0.w + g1.x + g1.y + g1.z + g1.w;
                v = ftanh(hps + sinv[b] * gg);
            }
            if (jt == 0) los[((size_t)t * BB + b) * RNND + kr] = v;  // slot t = lo(t-1)
        }
        sm[k * 33 + b] = v;
    }
    __syncthreads();
    int jq = tid & 15, b = tid >> 4;
    int j = jt * 64 + jq * 4;
    float4 acc = {0, 0, 0, 0};
#pragma unroll 4
    for (int k = 0; k < 256; ++k) {
        float4 w = *(const float4*)&W[(size_t)(k0 + k) * G3 + j];
        fma4(acc, w, sm[k * 33 + b]);
    }
    *(float4*)&ob[((size_t)ks * BB + b) * G3 + j] = acc;
}

// ---------------- K2: combine -> h(t); FINAL q/hpart slices. 512 blocks x 512 ----------------
// block (which, ls, b): thread j recomputes h[j] for its b (26KB partial reads),
// then ONE 64-col weight-slice GEMM (131KB) -> final q or hpart slice.
// 512 blocks = 2/CU -> latency overlap on the weight-slice stream.
__global__ void __launch_bounds__(512) k_qh(
    const float* __restrict__ mxp, const float* __restrict__ mhp,
    const float* __restrict__ gruB, const float* __restrict__ W2,
    const float* __restrict__ outW, const float* __restrict__ hin,
    float* __restrict__ hout, float* __restrict__ q,
    float* __restrict__ hpart) {
    __shared__ float sh[RNND];
    __shared__ float sred[512];
    int id = blockIdx.x;
    int b = id & 31, ls = (id >> 5) & 7, which = id >> 8;
    int tid = threadIdx.x;
    // phase 1: GRU combine -> h (thread j)
    {
        int j = tid;
        size_t m0 = ((size_t)0 * BB + b) * G3, m1 = ((size_t)1 * BB + b) * G3,
               m2 = ((size_t)2 * BB + b) * G3;
        float xz = gruB[j] + mxp[m0 + j] + mxp[m1 + j] + mxp[m2 + j];
        float xr = gruB[512 + j] + mxp[m0 + 512 + j] + mxp[m1 + 512 + j] + mxp[m2 + 512 + j];
        float xh = gruB[1024 + j] + mxp[m0 + 1024 + j] + mxp[m1 + 1024 + j] + mxp[m2 + 1024 + j];
        float rz = gruB[G3 + j] + mhp[m0 + j] + mhp[m1 + j];
        float rr = gruB[G3 + 512 + j] + mhp[m0 + 512 + j] + mhp[m1 + 512 + j];
        float rh = gruB[G3 + 1024 + j] + mhp[m0 + 1024 + j] + mhp[m1 + 1024 + j];
        float z = fsigmoid(xz + rz), r = fsigmoid(xr + rr);
        float hh = ftanh(xh + r * rh);
        float hn = z * hin[(size_t)b * RNND + j] + (1.f - z) * hh;
        sh[j] = hn;
        if (which == 0 && ls == 0) hout[(size_t)b * RNND + j] = hn;
    }
    __syncthreads();
    // phase 2: one 64-col slice, 8-way split-k in registers
    const float* W = which ? outW : W2;
    float* outp = which ? hpart : q;
    int c = ls * 64 + (tid & 63), kq = tid >> 6;
    int kb = kq * 64;
    float a = 0.f;
#pragma unroll 8
    for (int k = 0; k < 64; ++k) a += sh[kb + k] * W[(size_t)(kb + k) * 512 + c];
    sred[tid] = a;
    __syncthreads();
    if (tid < 64) {
        float acc = 0.f;
#pragma unroll
        for (int p = 0; p < 8; ++p) acc += sred[p * 64 + tid];
        outp[(size_t)b * RNND + ls * 64 + tid] = acc;
    }
}

// ---------------- K3: scores + exp + gdot partials. 256 blocks x 512 ----------------
__global__ void __launch_bounds__(512) k_attn(
    const float* __restrict__ q, const float* __restrict__ V,
    const float* __restrict__ fp, const float* __restrict__ G,
    float* __restrict__ gdotT, float* __restrict__ esumT) {
    __shared__ float sq[ATTD];
    __shared__ float sV[ATTD];
    __shared__ float se[64];
    int b = blockIdx.x >> 3, ls = blockIdx.x & 7, l0 = ls * 50;
    int tid = threadIdx.x;
    sq[tid] = q[(size_t)b * RNND + tid];
    sV[tid] = V[tid];
    if (tid >= 50 && tid < 64) se[tid] = 0.f;
    __syncthreads();
    int lane = tid & 63, wv = tid >> 6;
    float4 q0 = ((const float4*)sq)[lane], q1 = ((const float4*)sq)[64 + lane];
    float4 v0 = ((const float4*)sV)[lane], v1 = ((const float4*)sV)[64 + lane];
    for (int ll = wv; ll < 50; ll += 8) {
        const float4* row = (const float4*)(fp + ((size_t)b * LL + l0 + ll) * ATTD);
        float4 f0 = row[lane], f1 = row[64 + lane];
        float d = ftanh(f0.x + q0.x) * v0.x + ftanh(f0.y + q0.y) * v0.y +
                  ftanh(f0.z + q0.z) * v0.z + ftanh(f0.w + q0.w) * v0.w +
                  ftanh(f1.x + q1.x) * v1.x + ftanh(f1.y + q1.y) * v1.y +
                  ftanh(f1.z + q1.z) * v1.z + ftanh(f1.w + q1.w) * v1.w;
#pragma unroll
        for (int o = 32; o > 0; o >>= 1) d += __shfl_xor(d, o);
        if (lane == 0) se[ll] = __expf(d);  // |score| <= sum|V| ~ 20, fp32-safe
    }
    __syncthreads();
    if (tid < 64) {
        float x = se[tid];
#pragma unroll
        for (int o = 32; o > 0; o >>= 1) x += __shfl_xor(x, o);
        if (tid == 0) esumT[b * 8 + ls] = x;
    }
    // gdot partial over this l-chunk (thread = one column)
    float a = 0.f;
#pragma unroll 2
    for (int l = 0; l < 50; ++l)
        a += se[l] * G[((size_t)b * LL + l0 + l) * RNND + tid];
    gdotT[((size_t)b * RNND + tid) * 8 + ls] = a;
}

// ---------------- tail: lo(149) -> los slot 150. 32 blocks x 512 ----------------
__global__ void __launch_bounds__(512) k_lo_tail(
    const float* __restrict__ hpart, const float* __restrict__ gdotT,
    const float* __restrict__ esumT, float* __restrict__ los) {
    int b = blockIdx.x, tid = threadIdx.x;
    float4 e0 = *(const float4*)&esumT[b * 8];
    float4 e1 = *(const float4*)&esumT[b * 8 + 4];
    float inv = 1.f / (e0.x + e0.y + e0.z + e0.w + e1.x + e1.y + e1.z + e1.w);
    float hps = hpart[(size_t)b * RNND + tid];
    float4 g0 = *(const float4*)&gdotT[((size_t)b * RNND + tid) * 8];
    float4 g1 = *(const float4*)&gdotT[((size_t)b * RNND + tid) * 8 + 4];
    float gg = g0.x + g0.y + g0.z + g0.w + g1.x + g1.y + g1.z + g1.w;
    los[((size_t)TT * BB + b) * RNND + tid] = ftanh(hps + inv * gg);
}

// ---------------- final: logits = los[1..150] @ projW ----------------
__global__ void __launch_bounds__(256) k_final(
    const float* __restrict__ los, const float* __restrict__ Wp,
    float* __restrict__ out) {
    __shared__ float sa[64 * 68];
    __shared__ unsigned srow[64];
    int mt = blockIdx.x / 40, vt = blockIdx.x % 40;
    int r0 = mt * 64;
    int tid = threadIdx.x;
    if (tid < 64) {
        int r = r0 + tid;
        int bb = r / TT, t = r % TT;
        srow[tid] = (unsigned)(((size_t)(t + 1) * BB + bb) * RNND);
    }
    int aq = tid & 31, blg = tid >> 5;
    int v = vt * 128 + aq * 4;
    bool vok = v < VOCABD;
    float4 acc[8] = {};
    __syncthreads();
    for (int kc = 0; kc < RNND; kc += 64) {
        for (int it = 0; it < 16; ++it) {
            int lin = it * 256 + tid;
            int k = lin & 63, rl = lin >> 6;
            sa[k * 68 + rl] = los[srow[rl] + kc + k];
        }
        __syncthreads();
        if (vok) {
#pragma unroll 4
            for (int k = 0; k < 64; ++k) {
                float4 w = *(const float4*)&Wp[(size_t)(kc + k) * VOCABD + v];
                float4 s0 = *(const float4*)&sa[k * 68 + blg * 8];
                float4 s1 = *(const float4*)&sa[k * 68 + blg * 8 + 4];
                fma4(acc[0], w, s0.x); fma4(acc[1], w, s0.y);
                fma4(acc[2], w, s0.z); fma4(acc[3], w, s0.w);
                fma4(acc[4], w, s1.x); fma4(acc[5], w, s1.y);
                fma4(acc[6], w, s1.z); fma4(acc[7], w, s1.w);
            }
        }
        __syncthreads();
    }
    if (vok) {
#pragma unroll
        for (int i = 0; i < 8; ++i)
            *(float4*)&out[(size_t)(r0 + blg * 8 + i) * VOCABD + v] = acc[i];
    }
}

extern "C" void kernel_launch(void* const* d_in, const int* in_sizes, int n_in,
                              void* d_out, int out_size, void* d_ws, size_t ws_size,
                              hipStream_t stream) {
    const float* features  = (const float*)d_in[0];
    const float* initstate = (const float*)d_in[1];
    const float* emb       = (const float*)d_in[2];
    const float* gruK      = (const float*)d_in[3];
    const float* gruR      = (const float*)d_in[4];
    const float* gruB      = (const float*)d_in[5];
    const float* W1        = (const float*)d_in[6];
    const float* W2        = (const float*)d_in[7];
    const float* V         = (const float*)d_in[8];
    const float* outW      = (const float*)d_in[9];
    const float* projW     = (const float*)d_in[10];
    const int*   formula   = (const int*)d_in[11];
    float* logits = (float*)d_out;

    float* ws = (float*)d_ws;
    float* h0    = ws;                                  // 16,384
    float* h1    = h0 + (size_t)BB * RNND;              // 16,384
    float* mxp   = h1 + (size_t)BB * RNND;              // 147,456
    float* mhp   = mxp + (size_t)3 * BB * G3;           // 98,304
    float* q     = mhp + (size_t)2 * BB * G3;           // 16,384
    float* hpart = q + (size_t)BB * RNND;               // 16,384
    float* gdotT = hpart + (size_t)BB * RNND;           // 131,072
    float* esumT = gdotT + (size_t)BB * RNND * 8;       // 256
    float* los   = esumT + BB * 8;                      // 151 slots: 2,473,984
    float* fp    = los + (size_t)(TT + 1) * BB * RNND;  // 6,553,600
    float* G     = fp + (size_t)BB * LL * ATTD;         // 6,553,600

    // los slot 0 = lo(-1) = zeros; re-zeroed every call (deterministic).
    hipMemsetAsync(los, 0, (size_t)BB * RNND * sizeof(float), stream);
    hipMemcpyAsync(h0, initstate, (size_t)BB * RNND * sizeof(float),
                   hipMemcpyDeviceToDevice, stream);

    k_proj2<<<1600, 256, 0, stream>>>(features, W1, outW + (size_t)512 * RNND, fp, G);

    float* hin = h0;
    float* hout = h1;
    for (int t = 0; t < TT; ++t) {
        k_gates<<<120, 512, 0, stream>>>(emb, formula, gruK, gruR, hin,
                                         hpart, gdotT, esumT, mxp, mhp, los, t);
        k_qh<<<512, 512, 0, stream>>>(mxp, mhp, gruB, W2, outW, hin, hout, q, hpart);
        k_attn<<<256, 512, 0, stream>>>(q, V, fp, G, gdotT, esumT);
        float* tmp = hin; hin = hout; hout = tmp;
    }
    k_lo_tail<<<BB, 512, 0, stream>>>(hpart, gdotT, esumT, los);
    k_final<<<75 * 40, 256, 0, stream>>>(los, projW, logits);
}